// Round 1
// baseline (662.764 us; speedup 1.0000x reference)
//
#include <hip/hip_runtime.h>
#include <stdint.h>

#define FP8_MAX 448.0f
#define BSQ 128          // quantization block size
#define TM 128
#define TN 128
#define TK 128           // k-tile = scale block
#define NKB 32           // K / BSQ
#define SX_PAD 33        // padded stride for s_x LDS tile

typedef float f32x4 __attribute__((ext_vector_type(4)));

typedef const __attribute__((address_space(1))) uint8_t* gptr_t;
typedef __attribute__((address_space(3))) uint8_t* lptr_t;

// ---------------- activation quantization: per (row, 128-block) ----------------
__global__ void act_quant_kernel(const float* __restrict__ x,
                                 uint8_t* __restrict__ xq,
                                 float* __restrict__ sx,
                                 int M, int K) {
    int gid  = blockIdx.x * blockDim.x + threadIdx.x;
    int wave = gid >> 6;
    int lane = threadIdx.x & 63;
    int nkb  = K / BSQ;
    int row  = wave / nkb;
    int kb   = wave - row * nkb;
    if (row >= M) return;

    const float2 v = *(const float2*)(x + (size_t)row * K + kb * BSQ + lane * 2);
    float am = fmaxf(fabsf(v.x), fabsf(v.y));
#pragma unroll
    for (int off = 32; off >= 1; off >>= 1)
        am = fmaxf(am, __shfl_xor(am, off));

    float s = am / FP8_MAX;                    // matches reference: amax/448 in fp32
    if (lane == 0) sx[(size_t)row * nkb + kb] = s;

    float q0 = (am > 0.f) ? v.x / s : 0.f;     // fp32 IEEE division, then RNE->e4m3
    float q1 = (am > 0.f) ? v.y / s : 0.f;
    int packed = __builtin_amdgcn_cvt_pk_fp8_f32(q0, q1, 0, false);
    *(uint16_t*)(xq + (size_t)row * K + kb * BSQ + lane * 2) = (uint16_t)(packed & 0xffff);
}

// ---------------- weight cast fp32(fp8-representable) -> e4m3 bytes ----------------
__global__ void weight_quant_kernel(const float* __restrict__ w,
                                    uint8_t* __restrict__ wq, size_t n) {
    size_t i = ((size_t)blockIdx.x * blockDim.x + threadIdx.x) * 4;
    if (i >= n) return;
    float4 v = *(const float4*)(w + i);
    int lo = __builtin_amdgcn_cvt_pk_fp8_f32(v.x, v.y, 0, false);
    int hi = __builtin_amdgcn_cvt_pk_fp8_f32(v.z, v.w, 0, false);
    *(uint32_t*)(wq + i) = (uint32_t)((lo & 0xffff) | (hi << 16));
}

// ---------------- block-scaled fp8 GEMM: y[m,n] = sum_kb sx*sw * (fp8 dot) ----------------
__global__ __launch_bounds__(256, 2)
void fp8_gemm_kernel(const uint8_t* __restrict__ Aq,   // [M][K] e4m3
                     const uint8_t* __restrict__ Bq,   // [N][K] e4m3
                     const float*  __restrict__ sxg,   // [M][K/128]
                     const float*  __restrict__ swg,   // [N/128][K/128]
                     float* __restrict__ out,          // [M][N]
                     int M, int N, int K) {
    __shared__ uint8_t As[TM * TK];          // 16 KB, XOR-swizzled layout
    __shared__ uint8_t Bs[TN * TK];          // 16 KB
    __shared__ float   sxs[TM * SX_PAD];     // ~16.9 KB

    const int tid  = threadIdx.x;
    const int lane = tid & 63;
    const int wid  = tid >> 6;
    const int brow = blockIdx.y * TM;
    const int bcol = blockIdx.x * TN;
    const int nkb  = K / BSQ;

    // stage s_x tile for all 32 k-blocks (128 rows x 32 scales)
    for (int i = tid; i < TM * NKB; i += 256) {
        int r = i >> 5, c = i & 31;
        sxs[r * SX_PAD + c] = sxg[(size_t)(brow + r) * nkb + c];
    }

    const int wrow = (wid >> 1) * 64;
    const int wcol = (wid & 1) * 64;
    const int frow = lane & 15;      // fragment row (A) / col (B)
    const int fgrp = lane >> 4;      // k-group 0..3

    f32x4 acc[4][4];
#pragma unroll
    for (int i = 0; i < 4; ++i)
#pragma unroll
        for (int j = 0; j < 4; ++j) acc[i][j] = {0.f, 0.f, 0.f, 0.f};

    for (int kb = 0; kb < nkb; ++kb) {
        __syncthreads();   // previous compute done before overwriting LDS
        // stage A,B tiles: 16KB each; 4 rounds x 256 lanes x 16B
        // LDS layout linear; global SOURCE pre-swizzled: c ^= (row&7)<<4
#pragma unroll
        for (int r = 0; r < 4; ++r) {
            int slot = r * 256 + tid;          // 0..1023
            int row  = slot >> 3;              // 0..127
            int cb   = (slot & 7) << 4;        // 16B slot within row
            int scb  = cb ^ ((row & 7) << 4);  // pre-swizzled source col
            const uint8_t* gA = Aq + (size_t)(brow + row) * K + kb * TK + scb;
            const uint8_t* gB = Bq + (size_t)(bcol + row) * K + kb * TK + scb;
            lptr_t lA = (lptr_t)(As + (slot & ~63) * 16);   // wave-uniform base
            lptr_t lB = (lptr_t)(Bs + (slot & ~63) * 16);
            __builtin_amdgcn_global_load_lds((gptr_t)gA, lA, 16, 0, 0);
            __builtin_amdgcn_global_load_lds((gptr_t)gB, lB, 16, 0, 0);
        }
        float sw = swg[(size_t)(bcol >> 7) * nkb + kb];   // uniform per block
        __syncthreads();

        f32x4 pacc[4][4];   // fp8 partial for this 128-k block
#pragma unroll
        for (int kk = 0; kk < 4; ++kk) {
            long a[4], b[4];
            int c = kk * 32 + fgrp * 8;
#pragma unroll
            for (int mi = 0; mi < 4; ++mi) {
                int row = wrow + mi * 16 + frow;
                int sc  = c ^ ((row & 7) << 4);
                a[mi] = *(const long*)(As + row * TK + sc);
            }
#pragma unroll
            for (int ni = 0; ni < 4; ++ni) {
                int row = wcol + ni * 16 + frow;
                int sc  = c ^ ((row & 7) << 4);
                b[ni] = *(const long*)(Bs + row * TK + sc);
            }
#pragma unroll
            for (int mi = 0; mi < 4; ++mi)
#pragma unroll
                for (int ni = 0; ni < 4; ++ni) {
                    if (kk == 0) {
                        const f32x4 z = {0.f, 0.f, 0.f, 0.f};
                        pacc[mi][ni] = __builtin_amdgcn_mfma_f32_16x16x32_fp8_fp8(
                            a[mi], b[ni], z, 0, 0, 0);
                    } else {
                        pacc[mi][ni] = __builtin_amdgcn_mfma_f32_16x16x32_fp8_fp8(
                            a[mi], b[ni], pacc[mi][ni], 0, 0, 0);
                    }
                }
        }

        // fold partial into master accumulator with fp32 scales
#pragma unroll
        for (int mi = 0; mi < 4; ++mi) {
            float sxr[4];
#pragma unroll
            for (int r = 0; r < 4; ++r) {
                int rl = wrow + mi * 16 + fgrp * 4 + r;
                sxr[r] = sxs[rl * SX_PAD + kb] * sw;
            }
#pragma unroll
            for (int ni = 0; ni < 4; ++ni)
#pragma unroll
                for (int r = 0; r < 4; ++r)
                    acc[mi][ni][r] += pacc[mi][ni][r] * sxr[r];
        }
    }

    // epilogue: C/D layout col=lane&15, row=(lane>>4)*4+reg  [m89-verified]
#pragma unroll
    for (int mi = 0; mi < 4; ++mi)
#pragma unroll
        for (int ni = 0; ni < 4; ++ni)
#pragma unroll
            for (int r = 0; r < 4; ++r) {
                int row = brow + wrow + mi * 16 + fgrp * 4 + r;
                int col = bcol + wcol + ni * 16 + frow;
                out[(size_t)row * N + col] = acc[mi][ni][r];
            }
}

extern "C" void kernel_launch(void* const* d_in, const int* in_sizes, int n_in,
                              void* d_out, int out_size, void* d_ws, size_t ws_size,
                              hipStream_t stream) {
    const float* x   = (const float*)d_in[0];
    const float* w   = (const float*)d_in[1];
    const float* wsi = (const float*)d_in[2];
    float* out = (float*)d_out;

    const int K = 4096;
    const int M = in_sizes[0] / K;       // 4096
    const int N = in_sizes[1] / K;       // 16384

    uint8_t* xq = (uint8_t*)d_ws;                       // M*K bytes
    uint8_t* wq = xq + (size_t)M * K;                   // N*K bytes
    float*   sx = (float*)(wq + (size_t)N * K);         // M*(K/128) floats

    int waves = M * (K / BSQ);
    act_quant_kernel<<<dim3(waves / 4), dim3(256), 0, stream>>>(x, xq, sx, M, K);

    size_t wn = (size_t)N * K;
    weight_quant_kernel<<<dim3((unsigned)(wn / 4 / 256)), dim3(256), 0, stream>>>(w, wq, wn);

    dim3 grid(N / TN, M / TM);
    fp8_gemm_kernel<<<grid, dim3(256), 0, stream>>>(xq, wq, sx, wsi, out, M, N, K);
}

// Round 2
// 510.990 us; speedup vs baseline: 1.2970x; 1.2970x over previous
//
#include <hip/hip_runtime.h>
#include <stdint.h>

#define FP8_MAX 448.0f
#define BSQ 128          // quantization block size
#define TM 128
#define TN 128
#define NKB 32           // K / BSQ

typedef int   i32x4  __attribute__((ext_vector_type(4)));
typedef int   i32x8  __attribute__((ext_vector_type(8)));
typedef float f32x4v __attribute__((ext_vector_type(4)));
typedef float f32x16 __attribute__((ext_vector_type(16)));

typedef const __attribute__((address_space(1))) uint8_t* gptr_t;
typedef __attribute__((address_space(3))) uint8_t* lptr_t;

// 3-bit granule hash of a 5-bit row: rows {x,x+8,x+16,x+24} land on distinct
// granule columns -> b128 fragment reads are bank-balanced (8 lanes/granule).
__device__ __forceinline__ int hsw(int row) { return (row ^ (row >> 3)) & 7; }

// ---------------- activation quantization: per (row, 128-block) ----------------
__global__ void act_quant_kernel(const float* __restrict__ x,
                                 uint8_t* __restrict__ xq,
                                 float* __restrict__ sx,
                                 int M, int K) {
    int gid  = blockIdx.x * blockDim.x + threadIdx.x;
    int wave = gid >> 6;
    int lane = threadIdx.x & 63;
    int nkb  = K / BSQ;
    int row  = wave / nkb;
    int kb   = wave - row * nkb;
    if (row >= M) return;

    const float2 v = *(const float2*)(x + (size_t)row * K + kb * BSQ + lane * 2);
    float am = fmaxf(fabsf(v.x), fabsf(v.y));
#pragma unroll
    for (int off = 32; off >= 1; off >>= 1)
        am = fmaxf(am, __shfl_xor(am, off));

    float s = am / FP8_MAX;                    // matches reference: amax/448 in fp32
    if (lane == 0) sx[(size_t)row * nkb + kb] = s;

    float q0 = (am > 0.f) ? v.x / s : 0.f;     // fp32 IEEE division, then RNE->e4m3
    float q1 = (am > 0.f) ? v.y / s : 0.f;
    int packed = __builtin_amdgcn_cvt_pk_fp8_f32(q0, q1, 0, false);
    *(uint16_t*)(xq + (size_t)row * K + kb * BSQ + lane * 2) = (uint16_t)(packed & 0xffff);
}

// ---------------- weight cast fp32(fp8-representable) -> e4m3 bytes ----------------
__global__ void weight_quant_kernel(const float* __restrict__ w,
                                    uint8_t* __restrict__ wq, size_t n) {
    size_t i = ((size_t)blockIdx.x * blockDim.x + threadIdx.x) * 4;
    if (i >= n) return;
    float4 v = *(const float4*)(w + i);
    int lo = __builtin_amdgcn_cvt_pk_fp8_f32(v.x, v.y, 0, false);
    int hi = __builtin_amdgcn_cvt_pk_fp8_f32(v.z, v.w, 0, false);
    *(uint32_t*)(wq + i) = (uint32_t)((lo & 0xffff) | (hi << 16));
}

// ---------------- block-scaled fp8 GEMM via MX-MFMA (unit HW scales) ----------------
// y[m,n] = sum_kb sx[m,kb]*sw[nb,kb] * dot_fp8(x[m, kb*128:+128], w[n, kb*128:+128])
__global__ __launch_bounds__(256, 2)
void fp8_gemm_mx(const uint8_t* __restrict__ Aq,   // [M][K] e4m3
                 const uint8_t* __restrict__ Bq,   // [N][K] e4m3
                 const float*  __restrict__ sxg,   // [M][K/128]
                 const float*  __restrict__ swg,   // [N/128][K/128]
                 float* __restrict__ out,          // [M][N]
                 int M, int N, int K) {
    __shared__ uint8_t As[TM * BSQ];         // 16 KB, granule-swizzled rows
    __shared__ uint8_t Bs[TN * BSQ];         // 16 KB
    __shared__ float   sxs[NKB * TM];        // 16 KB, [kb][row], premult by sw

    const int tid  = threadIdx.x;
    const int lane = tid & 63;
    const int wid  = tid >> 6;
    const int brow = blockIdx.y * TM;
    const int bcol = blockIdx.x * TN;
    const int nkb  = K / BSQ;
    const int nb   = bcol >> 7;

    // premultiply scales once per block: sxs[kb][row] = sx[row][kb] * sw[nb][kb]
    for (int i = tid; i < NKB * TM; i += 256) {
        int row = i >> 5, kb = i & 31;       // consecutive lanes -> consecutive kb (coalesced)
        sxs[kb * TM + row] = sxg[(size_t)(brow + row) * nkb + kb]
                           * swg[(size_t)nb * nkb + kb];
    }

    const int wy = wid >> 1, wx = wid & 1;   // 2x2 wave grid, 64x64 per wave
    const int fl = lane & 31, hi = lane >> 5;

    const f32x16 zz = {0.f,0.f,0.f,0.f, 0.f,0.f,0.f,0.f,
                       0.f,0.f,0.f,0.f, 0.f,0.f,0.f,0.f};
    f32x16 acc[2][2];
#pragma unroll
    for (int i = 0; i < 2; ++i)
#pragma unroll
        for (int j = 0; j < 2; ++j) acc[i][j] = zz;

    for (int kb = 0; kb < nkb; ++kb) {
        __syncthreads();   // previous compute done before overwriting LDS
        // stage A,B tiles: LDS dest linear, global SOURCE pre-swizzled (involution)
#pragma unroll
        for (int r = 0; r < 4; ++r) {
            int slot = r * 256 + tid;          // 0..1023 16B-slots
            int row  = slot >> 3;              // 0..127
            int g    = (slot & 7) ^ hsw(row);  // swizzled source granule
            const uint8_t* gA = Aq + (size_t)(brow + row) * K + kb * BSQ + g * 16;
            const uint8_t* gB = Bq + (size_t)(bcol + row) * K + kb * BSQ + g * 16;
            __builtin_amdgcn_global_load_lds((gptr_t)gA, (lptr_t)(As + (slot & ~63) * 16), 16, 0, 0);
            __builtin_amdgcn_global_load_lds((gptr_t)gB, (lptr_t)(Bs + (slot & ~63) * 16), 16, 0, 0);
        }
        __syncthreads();

        // B fragments: row = N-col, lane hi takes k [32hi, 32hi+32) of each K=64 half
        i32x8 bfr[2][2];
#pragma unroll
        for (int fn = 0; fn < 2; ++fn) {
            int row = wx * 64 + fn * 32 + fl;
            int hh  = hsw(row);
            const uint8_t* base = Bs + row * BSQ;
#pragma unroll
            for (int kh = 0; kh < 2; ++kh) {
                int g0 = kh * 4 + hi * 2;
                i32x4 lo = *(const i32x4*)(base + (((g0    ) ^ hh) << 4));
                i32x4 h4 = *(const i32x4*)(base + (((g0 + 1) ^ hh) << 4));
                bfr[fn][kh] = (i32x8){lo.x, lo.y, lo.z, lo.w, h4.x, h4.y, h4.z, h4.w};
            }
        }

#pragma unroll
        for (int fm = 0; fm < 2; ++fm) {
            int arow = wy * 64 + fm * 32 + fl;
            int hh   = hsw(arow);
            const uint8_t* abase = As + arow * BSQ;
            i32x8 afr[2];
#pragma unroll
            for (int kh = 0; kh < 2; ++kh) {
                int g0 = kh * 4 + hi * 2;
                i32x4 lo = *(const i32x4*)(abase + (((g0    ) ^ hh) << 4));
                i32x4 h4 = *(const i32x4*)(abase + (((g0 + 1) ^ hh) << 4));
                afr[kh] = (i32x8){lo.x, lo.y, lo.z, lo.w, h4.x, h4.y, h4.z, h4.w};
            }
            // per-row scales for this fm: C/D row = 8q + 4hi + j  (reg = 4q+j)
            f32x4v s4[4];
#pragma unroll
            for (int q = 0; q < 4; ++q)
                s4[q] = *(const f32x4v*)&sxs[kb * TM + wy * 64 + fm * 32 + q * 8 + hi * 4];

#pragma unroll
            for (int fn = 0; fn < 2; ++fn) {
                // unit HW scales (e8m0 127 -> x1.0); exact fp32 fold below
                f32x16 p = __builtin_amdgcn_mfma_scale_f32_32x32x64_f8f6f4(
                    afr[0], bfr[fn][0], zz, 0, 0, 0, 127, 0, 127);
                p = __builtin_amdgcn_mfma_scale_f32_32x32x64_f8f6f4(
                    afr[1], bfr[fn][1], p, 0, 0, 0, 127, 0, 127);
#pragma unroll
                for (int q = 0; q < 4; ++q)
#pragma unroll
                    for (int j = 0; j < 4; ++j)
                        acc[fm][fn][q * 4 + j] += p[q * 4 + j] * s4[q][j];
            }
        }
    }

    // epilogue: C/D 32x32 layout col=lane&31, row=(reg&3)+8*(reg>>2)+4*(lane>>5)
#pragma unroll
    for (int fm = 0; fm < 2; ++fm)
#pragma unroll
        for (int fn = 0; fn < 2; ++fn)
#pragma unroll
            for (int q = 0; q < 4; ++q)
#pragma unroll
                for (int j = 0; j < 4; ++j) {
                    int row = brow + wy * 64 + fm * 32 + q * 8 + hi * 4 + j;
                    int col = bcol + wx * 64 + fn * 32 + fl;
                    out[(size_t)row * N + col] = acc[fm][fn][q * 4 + j];
                }
}

extern "C" void kernel_launch(void* const* d_in, const int* in_sizes, int n_in,
                              void* d_out, int out_size, void* d_ws, size_t ws_size,
                              hipStream_t stream) {
    const float* x   = (const float*)d_in[0];
    const float* w   = (const float*)d_in[1];
    const float* wsi = (const float*)d_in[2];
    float* out = (float*)d_out;

    const int K = 4096;
    const int M = in_sizes[0] / K;       // 4096
    const int N = in_sizes[1] / K;       // 16384

    uint8_t* xq = (uint8_t*)d_ws;                       // M*K bytes
    uint8_t* wq = xq + (size_t)M * K;                   // N*K bytes
    float*   sx = (float*)(wq + (size_t)N * K);         // M*(K/128) floats

    int waves = M * (K / BSQ);
    act_quant_kernel<<<dim3(waves / 4), dim3(256), 0, stream>>>(x, xq, sx, M, K);

    size_t wn = (size_t)N * K;
    weight_quant_kernel<<<dim3((unsigned)(wn / 4 / 256)), dim3(256), 0, stream>>>(w, wq, wn);

    dim3 grid(N / TN, M / TM);
    fp8_gemm_mx<<<grid, dim3(256), 0, stream>>>(xq, wq, sx, wsi, out, M, N, K);
}